// Round 9
// baseline (38.199 us; speedup 1.0000x reference)
//
#include <hip/hip_runtime.h>
#include <hip/hip_fp16.h>

#define N_ROWS 1024
#define DIM 256
#define HID 512
#define CTR 16          // uints per counter (64B cacheline stride)

typedef _Float16 half_t;
typedef __attribute__((ext_vector_type(8))) _Float16 half8v;
typedef __attribute__((ext_vector_type(16))) float f32x16;

#define WS_CH 2560      // halves per W chunk [64][40]

struct Params {
    const float* a;
    const float* b;
    const float* w[6];      // w0m,w0l,w1m,w1l,w2m,w2l (fp32, K x N)
    const float* bias[6];
    unsigned* c1;           // 32 counters, stride CTR, target 8
    unsigned* c2;           // 32 counters
    unsigned* c3;           // 16 counters, target 8
    unsigned* cs;           // 1 counter, target 64
    float* acc;
    unsigned* done;         // target 64
    float* part_s;          // [64][256]
    float* part_s2;         // [64][256]
    float* raw[2];          // [1024][256] f32 (mu, lv)
    half_t* h1[2];          // [1024][512] per net
    half_t* h2[2];
    float* out;
};

// ---------------- flag sync (r6-r8 proven; counters now cacheline-padded) ----
__device__ __forceinline__ void flag_add(unsigned* c) {
    asm volatile("s_waitcnt vmcnt(0)" ::: "memory");
    __syncthreads();
    if (threadIdx.x == 0)
        __hip_atomic_fetch_add(c, 1u, __ATOMIC_RELAXED, __HIP_MEMORY_SCOPE_AGENT);
}
__device__ __forceinline__ void flag_wait(unsigned* c, unsigned tgt) {
    if (threadIdx.x == 0) {
        while (__hip_atomic_load(c, __ATOMIC_RELAXED, __HIP_MEMORY_SCOPE_AGENT) < tgt)
            __builtin_amdgcn_s_sleep(1);
    }
    __syncthreads();
    asm volatile("" ::: "memory");
}

// ---------------- stage full W panel (K x 64 cols) -> Ws transposed f16 ----------------
// No barriers inside: caller's following barrier publishes it.
template <int K>
__device__ __forceinline__ void stage_W(const float* __restrict__ W, const int Nout,
                                        const int bn, half_t* __restrict__ Ws) {
    const int tid = threadIdx.x;
    const int wk0 = tid >> 4, wn0 = (tid & 15) * 4;
    #pragma unroll 2
    for (int c = 0; c < K / 32; ++c) {
        float4 v0 = *(const float4*)&W[(c * 32 + wk0) * Nout + bn + wn0];
        float4 v1 = *(const float4*)&W[(c * 32 + wk0 + 16) * Nout + bn + wn0];
        half_t* dst = Ws + c * WS_CH;
        #pragma unroll
        for (int s = 0; s < 2; ++s) {
            const int wk = wk0 + s * 16;
            float4 v = s ? v1 : v0;
            #pragma unroll
            for (int j = 0; j < 4; ++j) {
                const int row = wn0 + j;
                const int cidx = (((wk >> 3) ^ ((row >> 3) & 3)) * 8) + (wk & 7);
                float e = (j == 0) ? v.x : (j == 1) ? v.y : (j == 2) ? v.z : v.w;
                dst[row * 40 + cidx] = (half_t)e;
            }
        }
    }
}

// ---------------- GEMM phase: W in LDS, A direct-from-global, barrier-free ----
// Av: M x K (fp32 if AF32 else f16) row-major. C = act(A @ W + bias).
// MODE 0: relu -> f16 agent store; MODE 1: f32 agent store.
template <int K, int AF32, int MODE>
__device__ __forceinline__ void gemm_phase(const void* __restrict__ Av,
                                           const float* __restrict__ bias,
                                           void* __restrict__ Cp,
                                           const int Nout, const int bm, const int bn,
                                           const half_t* __restrict__ Ws) {
    const int tid = threadIdx.x;
    const int wave = tid >> 6, lane = tid & 63;
    const int wr = (wave >> 1) * 32, wc = (wave & 1) * 32;
    const int lr = lane & 31, hi = lane >> 5;
    const int rb = wc + lr;
    const int sb = (rb >> 3) & 3;
    const int b0off = (hi ^ sb) * 8, b1off = ((hi + 2) ^ sb) * 8;
    const int wrow = rb * 40;
    constexpr int NC = K >> 5;
    constexpr int PFA = AF32 ? 4 : 8;   // A register-prefetch depth (chunks)

    const float*  Af = (const float*)Av + (bm + wr + lr) * K;
    const half_t* Ah = (const half_t*)Av + (bm + wr + lr) * K;

    f32x16 acc;
    #pragma unroll
    for (int i = 0; i < 16; ++i) acc[i] = 0.f;

    half8v ah[8][2];     // f16 path buffers (static idx: loop fully unrolled)
    float4 af[4][4];     // fp32 path buffers
    half8v wb[4][2];     // W-fragment buffers

    #define ISSUE_A(c)                                                            \
        do {                                                                      \
            if (AF32) {                                                           \
                af[(c) & 3][0] = *(const float4*)&Af[(c) * 32 + hi * 8];          \
                af[(c) & 3][1] = *(const float4*)&Af[(c) * 32 + hi * 8 + 4];      \
                af[(c) & 3][2] = *(const float4*)&Af[(c) * 32 + 16 + hi * 8];     \
                af[(c) & 3][3] = *(const float4*)&Af[(c) * 32 + 16 + hi * 8 + 4]; \
            } else {                                                              \
                ah[(c) & 7][0] = *(const half8v*)&Ah[(c) * 32 + hi * 8];          \
                ah[(c) & 7][1] = *(const half8v*)&Ah[(c) * 32 + 16 + hi * 8];     \
            }                                                                     \
        } while (0)
    #define ISSUE_W(c)                                                            \
        do {                                                                      \
            const half_t* wp_ = Ws + (c) * WS_CH + wrow;                          \
            wb[(c) & 3][0] = *(const half8v*)&wp_[b0off];                         \
            wb[(c) & 3][1] = *(const half8v*)&wp_[b1off];                         \
        } while (0)

    #pragma unroll
    for (int c = 0; c < PFA; ++c) ISSUE_A(c);
    #pragma unroll
    for (int c = 0; c < 4; ++c) ISSUE_W(c);

    #pragma unroll
    for (int c = 0; c < NC; ++c) {
        half8v av0, av1;
        if (AF32) {
            float4 x0 = af[c & 3][0], x1 = af[c & 3][1];
            float4 x2 = af[c & 3][2], x3 = af[c & 3][3];
            av0[0] = (half_t)x0.x; av0[1] = (half_t)x0.y; av0[2] = (half_t)x0.z; av0[3] = (half_t)x0.w;
            av0[4] = (half_t)x1.x; av0[5] = (half_t)x1.y; av0[6] = (half_t)x1.z; av0[7] = (half_t)x1.w;
            av1[0] = (half_t)x2.x; av1[1] = (half_t)x2.y; av1[2] = (half_t)x2.z; av1[3] = (half_t)x2.w;
            av1[4] = (half_t)x3.x; av1[5] = (half_t)x3.y; av1[6] = (half_t)x3.z; av1[7] = (half_t)x3.w;
        } else {
            av0 = ah[c & 7][0];
            av1 = ah[c & 7][1];
        }
        if (c + PFA < NC) ISSUE_A(c + PFA);
        half8v bv0 = wb[c & 3][0], bv1 = wb[c & 3][1];
        if (c + 4 < NC) ISSUE_W(c + 4);
        acc = __builtin_amdgcn_mfma_f32_32x32x16_f16(av0, bv0, acc, 0, 0, 0);
        acc = __builtin_amdgcn_mfma_f32_32x32x16_f16(av1, bv1, acc, 0, 0, 0);
    }
    #undef ISSUE_A
    #undef ISSUE_W

    // epilogue: C/D layout col = lane&31, row = (reg&3)+8*(reg>>2)+4*(lane>>5)
    const int col = bn + wc + lr;
    const float bv = bias[col];
    const int rbase = bm + wr + 4 * hi;
    #pragma unroll
    for (int r = 0; r < 16; ++r) {
        const int row = rbase + (r & 3) + 8 * (r >> 2);
        float v = acc[r] + bv;
        if (MODE == 0) {
            v = fmaxf(v, 0.f);
            union { half_t h; unsigned short u; } cv;
            cv.h = (half_t)v;
            __hip_atomic_store((unsigned short*)Cp + row * Nout + col, cv.u,
                               __ATOMIC_RELAXED, __HIP_MEMORY_SCOPE_AGENT);
        } else {
            __hip_atomic_store((float*)Cp + row * Nout + col, v,
                               __ATOMIC_RELAXED, __HIP_MEMORY_SCOPE_AGENT);
        }
    }
}

// ---------------- single fused kernel ----------------
__global__ void __launch_bounds__(256) fused_kernel(Params p) {
    __shared__ alignas(16) char smem[81920];        // Ws only
    half_t* Ws = (half_t*)smem;

    const int bid = blockIdx.x, tid = threadIdx.x;
    const int net = bid & 1;
    const int m = (bid >> 1) & 15;
    const int n = bid >> 5;                 // 0..7
    const int bm = m * 64;

    // ---- L0: a[1024x256] @ w[net] -> h1[net] (relu) ----
    stage_W<DIM>(p.w[net], HID, n * 64, Ws);
    __syncthreads();                        // publish W0 panel
    gemm_phase<DIM, 1, 0>(p.a, p.bias[net], p.h1[net], HID, bm, n * 64, Ws);
    flag_add(p.c1 + (net * 16 + m) * CTR);

    // ---- colstats partials in sync shadow (net==1, n>=4) ----
    if (net == 1 && n >= 4) {
        const int idx = m * 4 + (n - 4);    // 0..63
        const int r0 = idx * 16, d = tid;
        float s = 0.f, s2 = 0.f;
        #pragma unroll
        for (int r = 0; r < 16; ++r) {
            float v = p.b[(r0 + r) * DIM + d];
            s += v; s2 = fmaf(v, v, s2);
        }
        __hip_atomic_store(&p.part_s[idx * DIM + d], s, __ATOMIC_RELAXED,
                           __HIP_MEMORY_SCOPE_AGENT);
        __hip_atomic_store(&p.part_s2[idx * DIM + d], s2, __ATOMIC_RELAXED,
                           __HIP_MEMORY_SCOPE_AGENT);
        flag_add(p.cs);
    }

    // ---- L1: h1 @ w[2+net] -> h2[net] (relu); W staged in the wait shadow ----
    stage_W<HID>(p.w[2 + net], HID, n * 64, Ws);
    flag_wait(p.c1 + (net * 16 + m) * CTR, 8);    // barrier also publishes W1 panel
    gemm_phase<HID, 0, 0>(p.h1[net], p.bias[2 + net], p.h2[net], HID, bm, n * 64, Ws);
    flag_add(p.c2 + (net * 16 + m) * CTR);

    // ---- L2 (n<4): h2 @ w[4+net] -> raw[net] f32 ----
    if (n < 4) {
        stage_W<HID>(p.w[4 + net], DIM, n * 64, Ws);
        flag_wait(p.c2 + (net * 16 + m) * CTR, 8);
        gemm_phase<HID, 0, 1>(p.h2[net], p.bias[4 + net], p.raw[net], DIM, bm, n * 64, Ws);
        flag_add(p.c3 + m * CTR);
    }

    // ---- loss (net==0, n>=4): 64 blocks x 16 rows ----
    if (net == 0 && n >= 4) {
        const int q = n - 4;
        flag_wait(p.cs, 64);
        flag_wait(p.c3 + m * CTR, 8);

        float* ebL  = (float*)smem;         // 256 (Ws dead for these blocks)
        float* eb2L = ebL + 256;            // 256
        float* bsum = ebL + 512;
        {
            const int d = tid;
            float s = 0.f, s2 = 0.f;
            #pragma unroll 8
            for (int j = 0; j < 64; ++j) {
                s  += p.part_s[j * DIM + d];
                s2 += p.part_s2[j * DIM + d];
            }
            ebL[d]  = s  * (1.f / (float)N_ROWS);
            eb2L[d] = s2 * (1.f / (float)N_ROWS);
        }
        if (tid == 0) *bsum = 0.f;
        __syncthreads();

        const float* mu_raw = p.raw[0];
        const float* lv_raw = p.raw[1];
        const int wave = tid >> 6, lane = tid & 63;
        const int rbase = m * 64 + q * 16;
        float wacc = 0.f;
        #pragma unroll
        for (int rr = 0; rr < 4; ++rr) {
            const int i = rbase + wave * 4 + rr;
            float m4[4], l4[4], ss = 0.f;
            #pragma unroll
            for (int t = 0; t < 4; ++t) {
                const int d = lane + t * 64;
                m4[t] = mu_raw[i * DIM + d];
                l4[t] = lv_raw[i * DIM + d];
                ss = fmaf(m4[t], m4[t], ss);
            }
            #pragma unroll
            for (int o = 32; o > 0; o >>= 1) ss += __shfl_xor(ss, o, 64);
            const float inv_norm = 1.f / fmaxf(sqrtf(ss), 1e-12f);
            #pragma unroll
            for (int t = 0; t < 4; ++t) {
                const int d = lane + t * 64;
                float mu = m4[t] * inv_norm;
                float lv = tanhf(l4[t]);
                float iv = expf(-lv);
                float diff2 = fmaf(mu, mu, fmaf(-2.f * mu, ebL[d], eb2L[d]));
                wacc += fmaf(diff2, iv, lv);
            }
        }
        #pragma unroll
        for (int o = 32; o > 0; o >>= 1) wacc += __shfl_xor(wacc, o, 64);
        if (lane == 0) atomicAdd(bsum, wacc);
        __syncthreads();
        if (tid == 0) {
            atomicAdd(p.acc, *bsum);
            asm volatile("s_waitcnt vmcnt(0)" ::: "memory");
            unsigned prev = __hip_atomic_fetch_add(p.done, 1u, __ATOMIC_RELAXED,
                                                   __HIP_MEMORY_SCOPE_AGENT);
            if (prev == 63u) {
                float v = __hip_atomic_load(p.acc, __ATOMIC_RELAXED, __HIP_MEMORY_SCOPE_AGENT);
                p.out[0] = v * (1.0f / (float)N_ROWS);
            }
        }
    }
}

extern "C" void kernel_launch(void* const* d_in, const int* in_sizes, int n_in,
                              void* d_out, int out_size, void* d_ws, size_t ws_size,
                              hipStream_t stream) {
    Params p;
    p.a = (const float*)d_in[0];
    p.b = (const float*)d_in[1];
    p.w[0] = (const float*)d_in[2];  p.bias[0] = (const float*)d_in[3];   // mu L0
    p.w[2] = (const float*)d_in[4];  p.bias[2] = (const float*)d_in[5];   // mu L1
    p.w[4] = (const float*)d_in[6];  p.bias[4] = (const float*)d_in[7];   // mu L2
    p.w[1] = (const float*)d_in[8];  p.bias[1] = (const float*)d_in[9];   // lv L0
    p.w[3] = (const float*)d_in[10]; p.bias[3] = (const float*)d_in[11];  // lv L1
    p.w[5] = (const float*)d_in[12]; p.bias[5] = (const float*)d_in[13];  // lv L2

    float* f = (float*)d_ws;
    p.c1   = (unsigned*)f;              // 32 counters * CTR   [0..511]
    p.c2   = (unsigned*)(f + 512);      // 32 counters * CTR   [512..1023]
    p.c3   = (unsigned*)(f + 1024);     // 16 counters * CTR   [1024..1279]
    p.cs   = (unsigned*)(f + 1280);
    p.acc  = f + 1296;
    p.done = (unsigned*)(f + 1312);
    p.part_s  = f + 2048;               // 64*256
    p.part_s2 = p.part_s + 64 * DIM;    // 64*256
    p.raw[0]  = p.part_s2 + 64 * DIM;   // 1024*256
    p.raw[1]  = p.raw[0] + N_ROWS * DIM;
    half_t* hb = (half_t*)(p.raw[1] + N_ROWS * DIM);
    p.h1[0] = hb;  hb += N_ROWS * HID;
    p.h1[1] = hb;  hb += N_ROWS * HID;
    p.h2[0] = hb;  hb += N_ROWS * HID;
    p.h2[1] = hb;  hb += N_ROWS * HID;
    p.out = (float*)d_out;

    hipMemsetAsync(d_ws, 0, 6144, stream);   // counters + acc + done
    fused_kernel<<<256, 256, 0, stream>>>(p);
}